// Round 7
// baseline (396.886 us; speedup 1.0000x reference)
//
#include <hip/hip_runtime.h>
#include <math.h>

// Problem constants
constexpr int BQ = 32;       // query batch
constexpr int C  = 256;      // channels
constexpr int HW = 4096;     // 64*64
constexpr int W  = 64;
constexpr int P  = 256;      // protos (4 * 8 * 8)
constexpr float THRESH = 0.95f;
constexpr float SCALE  = 20.0f;
constexpr float EPSF   = 1e-4f;
constexpr double EPSD  = 1e-4;
constexpr float GAP_THRESH = 2e-3f;   // split-bf16 dist err ~5e-4 -> 4x margin
constexpr int MAXSUS = 65536;

// d_out layout: pred [0, 131072) | debug_assign [131072, 262144) | proto_grid [262144, 278528)
constexpr int OUT_ASSIGN = BQ * HW;
constexpr int OUT_GRID   = 2 * BQ * HW;

typedef __attribute__((ext_vector_type(8))) short short8;
typedef __attribute__((ext_vector_type(16))) float floatx16;

static __device__ __forceinline__ unsigned short f2bf(float x) {
    unsigned u = __float_as_uint(x);
    u += 0x7FFFu + ((u >> 16) & 1u);     // round-to-nearest-even (no NaN inputs)
    return (unsigned short)(u >> 16);
}
static __device__ __forceinline__ float bf2f(unsigned short h) {
    return __uint_as_float(((unsigned)h) << 16);
}

// 32x32x16 fragment-order offset (ushort units): [ptile(8)][ks16(16)][h(2)][lane(64)][j(8)].
// lane = khi*32 + (col or row within 32); element j of lane <-> k-within-ks16 = khi*8 + j.
// A and B use the IDENTICAL map, so any HW k-permutation cancels in the contraction.
#define FRAGOFF32(pt, ks16, h, lane) (((((pt) * 16 + (ks16)) * 2 + (h)) * 64 + (lane)) * 8)

// async global->LDS, 16 B/lane; LDS dest = wave-uniform base + lane*16
static __device__ __forceinline__ void gl_lds16(const unsigned short* gp, unsigned short* lp) {
    __builtin_amdgcn_global_load_lds(
        (const __attribute__((address_space(1))) unsigned int*)gp,
        (__attribute__((address_space(3))) unsigned int*)lp, 16, 0, 0);
}

// ---------------------------------------------------------------------------
// Prep: pooled protos (fp64 normalize) -> split-bf16 32x32-frag-order pB + fp64
// pn64, valid flags, proto_grid output, zero suspect counter. Block=proto,
// thread=channel.
// ---------------------------------------------------------------------------
__global__ __launch_bounds__(256)
void prep_kernel(const float* __restrict__ sup_x, const float* __restrict__ sup_y,
                 float* __restrict__ out, unsigned short* __restrict__ pB,
                 double* __restrict__ pn64, int* __restrict__ valid,
                 int* __restrict__ counter)
{
    const int p = blockIdx.x;     // proto index = s*64 + gy*8 + gx
    const int t = threadIdx.x;    // channel
    const int s = p >> 6, gy = (p >> 3) & 7, gx = p & 7;

    const float* base = sup_x + ((size_t)(s * C + t)) * HW + (gy * 8) * W + gx * 8;
    double sum = 0.0;
#pragma unroll
    for (int r = 0; r < 8; ++r) {
        const float4 a  = *(const float4*)(base + r * W);
        const float4 bq = *(const float4*)(base + r * W + 4);
        sum += (double)a.x;  sum += (double)a.y;  sum += (double)a.z;  sum += (double)a.w;
        sum += (double)bq.x; sum += (double)bq.y; sum += (double)bq.z; sum += (double)bq.w;
    }
    const double mean = sum * (1.0 / 64.0);

    __shared__ double red[256];
    red[t] = mean * mean;
    __syncthreads();
    for (int off = 128; off > 0; off >>= 1) {
        if (t < off) red[t] += red[t + off];
        __syncthreads();
    }
    const double nrm = sqrt(red[0]);
    const double pnv = mean / fmax(nrm, EPSD);
    pn64[(size_t)p * C + t] = pnv;

    // split-bf16 32x32-frag-order store:
    // ptile = p>>5, col = p&31; ks16 = c>>4, khi = (c>>3)&1, j = c&7; lane = khi*32 + col
    const float pnf = (float)pnv;
    const unsigned short phi = f2bf(pnf);
    const unsigned short plo = f2bf(pnf - bf2f(phi));
    const int pt = p >> 5, ks16 = t >> 4, lane = (((t >> 3) & 1) << 5) | (p & 31), j = t & 7;
    pB[FRAGOFF32(pt, ks16, 0, lane) + j] = phi;
    pB[FRAGOFF32(pt, ks16, 1, lane) + j] = plo;

    bool mybit = false;
    if (t < 64) {
        const int r = t >> 3, k = t & 7;
        mybit = sup_y[s * HW + (gy * 8 + r) * W + gx * 8 + k] > THRESH;
    }
    const unsigned long long bm = __ballot(mybit);   // wave 0 carries t=0..63
    if (t == 0) {
        valid[p] = (__popcll(bm) > 32) ? 1 : 0;      // mask_pooled > 0.5
        if (p == 0) *counter = 0;
    }
    if (t < 64) {
        const int i = p * 64 + t;
        out[OUT_GRID + i] = (sup_y[i] > THRESH) ? 1.0f : 0.0f;
    }
}

// ---------------------------------------------------------------------------
// Main: split-bf16 MFMA dists + fused softmax/argmax/pred.
//
// R5 structure (32x32x16, half LDS reads at FULL occupancy) + R6 FIX:
// wave tile is 32 pos x 128 protos (wn = proto half), so the epilogue CANNOT
// be wave-local (R5 bug: each wn-half computed argmax/softmax over its own
// 128 protos and raced the output writes -> debug_assign absmax 254 while
// pred squeaked by). Now: per-wave shuffle-reduce produces per-position
// partials {m1, m2, id, se, sw} -> LDS [wn][64 pos] (2.5 KiB), one barrier,
// then threads t<64 combine the halves with exact online-softmax algebra:
//   M = max(m1a,m1b) (>= tie-break: half-A ids < half-B ids -> first occur.)
//   second_global = max(m2_winner, m1_loser)    [gap check]
//   se = se_a*exp(m1a-M) + se_b*exp(m1b-M), sw likewise.
// Single writer per position; single suspect atomic.
// acc = 4 x floatx16 = 64 AGPR -> (256,4), 4 blocks/CU, LDS 36.3 KB (x4 =
// 145 KB <= 160). Spill tripwire: WRITE_SIZE > 20 MB.
// C/D layout (HW-verified m74/m101): col=lane&31, row=(r&3)+8*(r>>2)+4*(lane>>5).
// (R7 = identical resubmit of R6: the R6 round died on container infra,
// never reached hardware.)
// ---------------------------------------------------------------------------
__global__ __launch_bounds__(256, 4)
void dist_kernel(const float* __restrict__ qry, const unsigned short* __restrict__ pB,
                 const int* __restrict__ valid, float* __restrict__ out,
                 int* __restrict__ counter, int* __restrict__ suspects)
{
    __shared__ unsigned short ldsB[8 * 2 * 2 * 64 * 8];   // 32 KiB: chunk c=(pt*4+hf*2+h) of 1KiB
    __shared__ int validLds[P];                           // 1 KiB
    __shared__ float part_m1[2][64], part_m2[2][64], part_se[2][64], part_sw[2][64];
    __shared__ int   part_id[2][64];                      // 2.5 KiB partials

    const int t  = threadIdx.x;
    const int w  = t >> 6;        // wave
    const int l  = t & 63;
    const int lr = l & 31;        // row (pos) for A / col (proto) for B
    const int lh = l >> 5;        // k-half selector within ks16
    const int wp = w >> 1;        // pos half   (0/1)
    const int wn = w & 1;         // proto half (0/1)

    const int b    = blockIdx.x >> 6;
    const int pos0 = (blockIdx.x & 63) * 64;

    validLds[t] = valid[t];

    // lane covers pos = pos0 + wp*32 + lr; channel c = ks*32 + hf*16 + lh*8 + j
    const float* qp = qry + (size_t)b * C * HW + pos0 + wp * 32 + lr;

    floatx16 acc[4];
#pragma unroll
    for (int nt = 0; nt < 4; ++nt)
#pragma unroll
        for (int r = 0; r < 16; ++r) acc[nt][r] = 0.f;

    // prologue: issue A loads for ks=0 (drained by the first barrier)
    float vbuf[2][8];   // [hf][j]
#pragma unroll
    for (int hf = 0; hf < 2; ++hf)
#pragma unroll
        for (int j = 0; j < 8; ++j)
            vbuf[hf][j] = qp[(size_t)(hf * 16 + lh * 8 + j) * HW];

    float ssq = 0.f;
#pragma unroll
    for (int ks = 0; ks < 8; ++ks) {
        __syncthreads();                 // (a) all waves done reading ldsB(ks-1); iter0: validLds
        // stage B(ks): 32 chunks of 1 KiB; wave w stages chunks w*8..w*8+7
        // chunk c = pt*4 + hf*2 + h  (pt = c>>2, hf = (c>>1)&1, h = c&1)
#pragma unroll
        for (int i = 0; i < 8; ++i) {
            const int c = w * 8 + i, pt = c >> 2, hf = (c >> 1) & 1, h = c & 1;
            gl_lds16(pB + FRAGOFF32(pt, ks * 2 + hf, h, 0) + l * 8,
                     &ldsB[c * 512]);
        }
        // convert A(ks) (VALU overlaps the B-stage flight); cur vbuf dies here
        short8 ah[2], al[2];
#pragma unroll
        for (int hf = 0; hf < 2; ++hf)
#pragma unroll
            for (int j = 0; j < 8; ++j) {
                const float v = vbuf[hf][j];
                ssq = fmaf(v, v, ssq);
                const unsigned short hi = f2bf(v);
                ah[hf][j] = (short)hi;
                al[hf][j] = (short)f2bf(v - bf2f(hi));
            }
        // prefetch A(ks+1) (in flight until barrier (b) drains vmcnt)
        if (ks < 7) {
#pragma unroll
            for (int hf = 0; hf < 2; ++hf)
#pragma unroll
                for (int j = 0; j < 8; ++j)
                    vbuf[hf][j] = qp[(size_t)((ks + 1) * 32 + hf * 16 + lh * 8 + j) * HW];
        }
        __syncthreads();                 // (b) vmcnt drained -> B(ks) visible
#pragma unroll
        for (int nt = 0; nt < 4; ++nt) {
            const int g = wn * 4 + nt;   // global proto-tile
#pragma unroll
            for (int hf = 0; hf < 2; ++hf) {
                const short8 bh = *(const short8*)&ldsB[((g * 2 + hf) * 2 + 0) * 512 + l * 8];
                const short8 bl = *(const short8*)&ldsB[((g * 2 + hf) * 2 + 1) * 512 + l * 8];
                acc[nt] = __builtin_amdgcn_mfma_f32_32x32x16_bf16(ah[hf], bh, acc[nt], 0, 0, 0);
                acc[nt] = __builtin_amdgcn_mfma_f32_32x32x16_bf16(ah[hf], bl, acc[nt], 0, 0, 0);
                acc[nt] = __builtin_amdgcn_mfma_f32_32x32x16_bf16(al[hf], bh, acc[nt], 0, 0, 0);
            }
        }
    }

    // ||q||^2 for pos lr: combine the two k-halves (lanes l and l^32)
    ssq += __shfl_xor(ssq, 32);
    const float scalev = SCALE / fmaxf(sqrtf(ssq), EPSF);

    // ---- epilogue part 1: per-wave partials over its 128 protos ----
    // C/D: proto = (wn*4+nt)*32 + lr, pos-in-32 = 4*lh + (r&3) + 8*(r>>2)
    int vbits = 0;
#pragma unroll
    for (int nt = 0; nt < 4; ++nt) vbits |= validLds[(wn * 4 + nt) * 32 + lr] << nt;

    float scr[16];
#pragma unroll
    for (int r = 0; r < 16; ++r)
        scr[r] = __shfl(scalev, 4 * lh + (r & 3) + 8 * (r >> 2));   // lane 'pos' holds its scale
#pragma unroll
    for (int nt = 0; nt < 4; ++nt)
#pragma unroll
        for (int r = 0; r < 16; ++r) acc[nt][r] *= scr[r];   // positive factor: ordering-safe

#pragma unroll
    for (int r = 0; r < 16; ++r) {
        // pass 1: max / argmax (first occurrence) / 2nd-max over this wave's 128 protos
        float m1 = -INFINITY, m2 = -INFINITY; int id = 0x7fffffff;
#pragma unroll
        for (int nt = 0; nt < 4; ++nt) {
            if (vbits & (1 << nt)) {
                const float d = acc[nt][r];
                if (d > m1)      { m2 = m1; m1 = d; id = (wn * 4 + nt) * 32 + lr; }
                else if (d > m2) { m2 = d; }
            }
        }
#pragma unroll
        for (int sh = 1; sh < 32; sh <<= 1) {   // reduce over lr (protos), within 32-half
            const float om1 = __shfl_xor(m1, sh);
            const float om2 = __shfl_xor(m2, sh);
            const int   oid = __shfl_xor(id, sh);
            if (om1 > m1) { m2 = fmaxf(m1, om2); m1 = om1; id = oid; }
            else { if (om1 == m1 && oid < id) id = oid; m2 = fmaxf(m2, om1); }
        }
        // pass 2: softmax partials relative to own-half max m1
        float se = 0.f, sw = 0.f;
#pragma unroll
        for (int nt = 0; nt < 4; ++nt) {
            if (vbits & (1 << nt)) {
                const float d = acc[nt][r];
                const float e = __expf(d - m1);
                se += e; sw = fmaf(e, d, sw);
            }
        }
#pragma unroll
        for (int sh = 1; sh < 32; sh <<= 1) {
            se += __shfl_xor(se, sh);
            sw += __shfl_xor(sw, sh);
        }
        if (lr == 0) {
            const int pidx = wp * 32 + 4 * lh + (r & 3) + 8 * (r >> 2);   // pos within block
            part_m1[wn][pidx] = m1;
            part_m2[wn][pidx] = m2;
            part_id[wn][pidx] = id;
            part_se[wn][pidx] = se;
            part_sw[wn][pidx] = sw;
        }
    }
    __syncthreads();

    // ---- epilogue part 2: combine proto-halves; thread t<64 owns position t ----
    if (t < 64) {
        const float m1a = part_m1[0][t], m1b = part_m1[1][t];
        float M, m2g; int id;
        if (m1a >= m1b) { M = m1a; id = part_id[0][t]; m2g = fmaxf(part_m2[0][t], m1b); }
        else            { M = m1b; id = part_id[1][t]; m2g = fmaxf(part_m2[1][t], m1a); }
        const float ea = __expf(m1a - M), eb = __expf(m1b - M);
        const float se = part_se[0][t] * ea + part_se[1][t] * eb;
        const float sw = part_sw[0][t] * ea + part_sw[1][t] * eb;
        const int posg = b * HW + pos0 + t;
        out[OUT_ASSIGN + posg] = (float)id;
        if (M - m2g < GAP_THRESH) {          // near-tie -> exact fp64 recheck
            const int slot = atomicAdd(counter, 1);
            if (slot < MAXSUS) suspects[slot] = posg;
        }
        out[posg] = sw / se;
    }
}

// ---------------------------------------------------------------------------
// Recheck: exact fp64 argmax for near-tie positions. Batches 16 suspects per
// block iteration: q columns staged to LDS in parallel, protos streamed once
// per batch. First-occurrence tie-break like jnp.argmax.
// ---------------------------------------------------------------------------
__global__ __launch_bounds__(256)
void recheck_kernel(const float* __restrict__ qry, const double* __restrict__ pn64,
                    const int* __restrict__ valid, const int* __restrict__ counter,
                    const int* __restrict__ suspects, float* __restrict__ out)
{
    __shared__ float  qsh[16][256];
    __shared__ double pd[4];
    __shared__ int    pi[4];
    const int t = threadIdx.x;
    const int w = t >> 6, l = t & 63;
    int n = *counter; if (n > MAXSUS) n = MAXSUS;
    const int nb = (n + 15) >> 4;

    for (int batch = blockIdx.x; batch < nb; batch += gridDim.x) {
        const int base = batch * 16;
        const int cnt = (n - base < 16) ? (n - base) : 16;
        for (int s = 0; s < cnt; ++s) {
            const int pos = suspects[base + s];
            qsh[s][t] = qry[(size_t)(pos >> 12) * (C * HW) + (size_t)t * HW + (pos & (HW - 1))];
        }
        __syncthreads();

        double acc[16];
#pragma unroll
        for (int s = 0; s < 16; ++s) acc[s] = 0.0;
        const double* pr = pn64 + (size_t)t * C;   // thread t = proto t
#pragma unroll 4
        for (int c = 0; c < C; ++c) {
            const double pv = pr[c];
#pragma unroll
            for (int s = 0; s < 16; ++s) acc[s] = fma((double)qsh[s][c], pv, acc[s]);
        }
        const bool vl = valid[t] != 0;
        for (int s = 0; s < cnt; ++s) {
            double dv = vl ? acc[s] : -INFINITY;
            int id = t;
#pragma unroll
            for (int sh = 1; sh < 64; sh <<= 1) {
                const double od = __shfl_xor(dv, sh);
                const int    oi = __shfl_xor(id, sh);
                if (od > dv || (od == dv && oi < id)) { dv = od; id = oi; }
            }
            if (l == 0) { pd[w] = dv; pi[w] = id; }
            __syncthreads();
            if (t == 0) {
                double bd = pd[0]; int bi = pi[0];
                for (int ww = 1; ww < 4; ++ww)
                    if (pd[ww] > bd || (pd[ww] == bd && pi[ww] < bi)) { bd = pd[ww]; bi = pi[ww]; }
                out[OUT_ASSIGN + suspects[base + s]] = (float)bi;
            }
            __syncthreads();
        }
    }
}

// ---------------------------------------------------------------------------
extern "C" void kernel_launch(void* const* d_in, const int* in_sizes, int n_in,
                              void* d_out, int out_size, void* d_ws, size_t ws_size,
                              hipStream_t stream)
{
    const float* qry   = (const float*)d_in[0];
    const float* sup_x = (const float*)d_in[1];
    const float* sup_y = (const float*)d_in[2];
    float* out = (float*)d_out;
    char*  ws  = (char*)d_ws;

    // ws layout (~1.03 MiB total)
    unsigned short* pB       = (unsigned short*)(ws);            // 256 KiB frag-order split-bf16 protos
    double*         pn64     = (double*)(ws + 256 * 1024);       // 512 KiB
    int*            valid    = (int*)(ws + 768 * 1024);          // 1 KiB
    int*            counter  = (int*)(ws + 768 * 1024 + 1024);   // 4 B
    int*            suspects = (int*)(ws + 768 * 1024 + 2048);   // 256 KiB

    prep_kernel<<<dim3(P), dim3(256), 0, stream>>>(sup_x, sup_y, out, pB, pn64, valid, counter);
    dist_kernel<<<dim3(BQ * (HW / 64)), dim3(256), 0, stream>>>(qry, pB, valid, out, counter, suspects);
    recheck_kernel<<<dim3(256), dim3(256), 0, stream>>>(qry, pn64, valid, counter, suspects, out);
}

// Round 8
// 275.584 us; speedup vs baseline: 1.4402x; 1.4402x over previous
//
#include <hip/hip_runtime.h>
#include <math.h>

// Problem constants
constexpr int BQ = 32;       // query batch
constexpr int C  = 256;      // channels
constexpr int HW = 4096;     // 64*64
constexpr int W  = 64;
constexpr int P  = 256;      // protos (4 * 8 * 8)
constexpr float THRESH = 0.95f;
constexpr float SCALE  = 20.0f;
constexpr float EPSF   = 1e-4f;
constexpr double EPSD  = 1e-4;
constexpr float GAP_THRESH = 2e-3f;   // split-bf16 dist err ~5e-4 -> 4x margin
constexpr int MAXSUS = 65536;

// d_out layout: pred [0, 131072) | debug_assign [131072, 262144) | proto_grid [262144, 278528)
constexpr int OUT_ASSIGN = BQ * HW;
constexpr int OUT_GRID   = 2 * BQ * HW;

typedef __attribute__((ext_vector_type(8))) short short8;
typedef __attribute__((ext_vector_type(4))) float floatx4;

static __device__ __forceinline__ unsigned short f2bf(float x) {
    unsigned u = __float_as_uint(x);
    u += 0x7FFFu + ((u >> 16) & 1u);     // round-to-nearest-even (no NaN inputs)
    return (unsigned short)(u >> 16);
}
static __device__ __forceinline__ float bf2f(unsigned short h) {
    return __uint_as_float(((unsigned)h) << 16);
}

// Fragment-order offset (ushort units): [tile][ks][h][lane][j], lane = quad*16 + idx,
// element j of lane <-> k = ks*32 + quad*8 + j. A and B use the IDENTICAL map, so
// any k-permutation cancels in the MFMA contraction.
#define FRAGOFF(tile, ks, h, lane) (((((tile) * 8 + (ks)) * 2 + (h)) * 64 + (lane)) * 8)

// async global->LDS, 16 B/lane; LDS dest = wave-uniform base + lane*16
static __device__ __forceinline__ void gl_lds16(const unsigned short* gp, unsigned short* lp) {
    __builtin_amdgcn_global_load_lds(
        (const __attribute__((address_space(1))) unsigned int*)gp,
        (__attribute__((address_space(3))) unsigned int*)lp, 16, 0, 0);
}

// ---------------------------------------------------------------------------
// Prep: pooled protos (fp64 normalize) -> split-bf16 frag-order pB + fp64 pn64,
// valid flags, proto_grid output, zero suspect counter. Block=proto, thread=channel.
// (16x16 frag order — matches the R2 dist kernel, which is re-instated below.)
// ---------------------------------------------------------------------------
__global__ __launch_bounds__(256)
void prep_kernel(const float* __restrict__ sup_x, const float* __restrict__ sup_y,
                 float* __restrict__ out, unsigned short* __restrict__ pB,
                 double* __restrict__ pn64, int* __restrict__ valid,
                 int* __restrict__ counter)
{
    const int p = blockIdx.x;     // proto index = s*64 + gy*8 + gx
    const int t = threadIdx.x;    // channel
    const int s = p >> 6, gy = (p >> 3) & 7, gx = p & 7;

    const float* base = sup_x + ((size_t)(s * C + t)) * HW + (gy * 8) * W + gx * 8;
    double sum = 0.0;
#pragma unroll
    for (int r = 0; r < 8; ++r) {
        const float4 a  = *(const float4*)(base + r * W);
        const float4 bq = *(const float4*)(base + r * W + 4);
        sum += (double)a.x;  sum += (double)a.y;  sum += (double)a.z;  sum += (double)a.w;
        sum += (double)bq.x; sum += (double)bq.y; sum += (double)bq.z; sum += (double)bq.w;
    }
    const double mean = sum * (1.0 / 64.0);

    __shared__ double red[256];
    red[t] = mean * mean;
    __syncthreads();
    for (int off = 128; off > 0; off >>= 1) {
        if (t < off) red[t] += red[t + off];
        __syncthreads();
    }
    const double nrm = sqrt(red[0]);
    const double pnv = mean / fmax(nrm, EPSD);
    pn64[(size_t)p * C + t] = pnv;

    // split-bf16 frag-order store: nt=p>>4, n-idx=p&15; ks=c>>5, quad=(c>>3)&3, j=c&7
    const float pnf = (float)pnv;
    const unsigned short phi = f2bf(pnf);
    const unsigned short plo = f2bf(pnf - bf2f(phi));
    const int nt = p >> 4, ks = t >> 5, lane = (((t >> 3) & 3) << 4) | (p & 15), j = t & 7;
    pB[FRAGOFF(nt, ks, 0, lane) + j] = phi;
    pB[FRAGOFF(nt, ks, 1, lane) + j] = plo;

    bool mybit = false;
    if (t < 64) {
        const int r = t >> 3, k = t & 7;
        mybit = sup_y[s * HW + (gy * 8 + r) * W + gx * 8 + k] > THRESH;
    }
    const unsigned long long bm = __ballot(mybit);   // wave 0 carries t=0..63
    if (t == 0) {
        valid[p] = (__popcll(bm) > 32) ? 1 : 0;      // mask_pooled > 0.5
        if (p == 0) *counter = 0;
    }
    if (t < 64) {
        const int i = p * 64 + t;
        out[OUT_GRID + i] = (sup_y[i] > THRESH) ? 1.0f : 0.0f;
    }
}

// ---------------------------------------------------------------------------
// Main: split-bf16 MFMA dists + fused softmax/argmax/pred.
// EXACT R2 KERNEL (measured 87 us, VGPR 64, Occ 37%, MfmaUtil 23%, no spills).
// R8: re-instated verbatim after the 32x32x16 experiment (R5-R7) failed on
// register pressure: doubling the A path (16 in-flight strided loads + addr
// VGPRs + dbuf vbuf) overflowed the 64-arch-reg cap of (256,4)+64AGPR ->
// 294 MB scratch spill traffic, dist 197 us. The 16x16 structure is the one
// that fits the full-occupancy register budget.
// Block = 64 positions (4 waves); wave w owns pos-tile w (16 pos) x ALL 256
// protos. Per-ks A streaming: 8-float prefetch buffer + 8-VGPR fragment;
// convert VALU fills the B-stage drain window.
// ---------------------------------------------------------------------------
__global__ __launch_bounds__(256, 4)
void dist_kernel(const float* __restrict__ qry, const unsigned short* __restrict__ pB,
                 const int* __restrict__ valid, float* __restrict__ out,
                 int* __restrict__ counter, int* __restrict__ suspects)
{
    __shared__ unsigned short ldsB[16 * 2 * 64 * 8];   // 32 KiB: [nt][h][lane][j]
    __shared__ int validLds[P];                        // 1 KiB

    const int t    = threadIdx.x;
    const int w    = t >> 6;      // wave -> pos-tile
    const int l    = t & 63;
    const int quad = l >> 4;
    const int m    = l & 15;

    const int b    = blockIdx.x >> 6;
    const int pos0 = (blockIdx.x & 63) * 64;

    validLds[t] = valid[t];

    // lane l covers pos = pos0 + w*16 + m, k = ks*32 + quad*8 + j
    const float* qp = qry + (size_t)b * C * HW + pos0 + w * 16 + m;

    floatx4 acc[16];
#pragma unroll
    for (int nt = 0; nt < 16; ++nt) acc[nt] = (floatx4){0.f, 0.f, 0.f, 0.f};

    // prologue: issue A loads for ks=0 (drained by the first barrier)
    float vbuf[8];
#pragma unroll
    for (int j = 0; j < 8; ++j)
        vbuf[j] = qp[(size_t)(quad * 8 + j) * HW];

    float ssq = 0.f;
#pragma unroll
    for (int ks = 0; ks < 8; ++ks) {
        __syncthreads();                 // (a) prev chunk's LDS readers done; A(ks) drained
        // stage B(ks): 32 chunks of 1 KiB; wave w stages chunks w*8..w*8+7
#pragma unroll
        for (int i = 0; i < 8; ++i) {
            const int idx = w * 8 + i, nt = idx >> 1, h = idx & 1;
            gl_lds16(pB + FRAGOFF(nt, ks, h, 0) + l * 8,
                     &ldsB[(nt * 2 + h) * 512]);
        }
        // convert A(ks) from vbuf (VALU work overlaps the B-stage flight)
        short8 h8, l8;
#pragma unroll
        for (int j = 0; j < 8; ++j) {
            const float v = vbuf[j];
            ssq = fmaf(v, v, ssq);
            const unsigned short hi = f2bf(v);
            h8[j] = (short)hi;
            l8[j] = (short)f2bf(v - bf2f(hi));
        }
        // prefetch A(ks+1) (drained at barrier (b) below; ready next iteration)
        if (ks < 7) {
#pragma unroll
            for (int j = 0; j < 8; ++j)
                vbuf[j] = qp[(size_t)((ks + 1) * 32 + quad * 8 + j) * HW];
        }
        __syncthreads();                 // (b) vmcnt drained -> B(ks) visible
#pragma unroll
        for (int nt = 0; nt < 16; ++nt) {
            const short8 bh = *(const short8*)&ldsB[((nt * 2 + 0) * 64 + l) * 8];
            const short8 bl = *(const short8*)&ldsB[((nt * 2 + 1) * 64 + l) * 8];
            acc[nt] = __builtin_amdgcn_mfma_f32_16x16x32_bf16(h8, bh, acc[nt], 0, 0, 0);
            acc[nt] = __builtin_amdgcn_mfma_f32_16x16x32_bf16(h8, bl, acc[nt], 0, 0, 0);
            acc[nt] = __builtin_amdgcn_mfma_f32_16x16x32_bf16(l8, bh, acc[nt], 0, 0, 0);
        }
    }

    // ||q||^2 for pos w*16+m: sum the 4 quads (lanes differing in bits 4,5)
    ssq += __shfl_xor(ssq, 16);
    ssq += __shfl_xor(ssq, 32);
    const float scalev = SCALE / fmaxf(sqrtf(ssq), EPSF);

    // ---- epilogue (wave-local). C/D: proto = nt*16 + m, pos-in-tile = quad*4 + r ----
    int vbits = 0;
#pragma unroll
    for (int nt = 0; nt < 16; ++nt) vbits |= validLds[nt * 16 + m] << nt;

    float scr[4];
#pragma unroll
    for (int r = 0; r < 4; ++r) scr[r] = __shfl(scalev, quad * 4 + r);   // lane quad*4+r holds pos w*16+quad*4+r
#pragma unroll
    for (int nt = 0; nt < 16; ++nt)
#pragma unroll
        for (int r = 0; r < 4; ++r) acc[nt][r] *= scr[r];   // positive factor: ordering-safe

#pragma unroll
    for (int r = 0; r < 4; ++r) {
        // pass 1: max / argmax (first occurrence) / 2nd-max
        float m1 = -INFINITY, m2 = -INFINITY; int id = 0x7fffffff;
#pragma unroll
        for (int nt = 0; nt < 16; ++nt) {
            if (vbits & (1 << nt)) {
                const float d = acc[nt][r];
                if (d > m1)      { m2 = m1; m1 = d; id = nt * 16 + m; }
                else if (d > m2) { m2 = d; }
            }
        }
#pragma unroll
        for (int sh = 1; sh < 16; sh <<= 1) {   // reduce over m (protos), within quad
            const float om1 = __shfl_xor(m1, sh);
            const float om2 = __shfl_xor(m2, sh);
            const int   oid = __shfl_xor(id, sh);
            if (om1 > m1) { m2 = fmaxf(m1, om2); m1 = om1; id = oid; }
            else { if (om1 == m1 && oid < id) id = oid; m2 = fmaxf(m2, om1); }
        }
        const int posg = b * HW + pos0 + w * 16 + quad * 4 + r;
        if (m == 0) {
            out[OUT_ASSIGN + posg] = (float)id;
            if (m1 - m2 < GAP_THRESH) {          // near-tie -> exact fp64 recheck
                const int slot = atomicAdd(counter, 1);
                if (slot < MAXSUS) suspects[slot] = posg;
            }
        }
        // pass 2: softmax denominator and weighted sum (all lanes hold m1)
        float se = 0.f, sw = 0.f;
#pragma unroll
        for (int nt = 0; nt < 16; ++nt) {
            if (vbits & (1 << nt)) {
                const float d = acc[nt][r];
                const float e = __expf(d - m1);
                se += e; sw = fmaf(e, d, sw);
            }
        }
#pragma unroll
        for (int sh = 1; sh < 16; sh <<= 1) {
            se += __shfl_xor(se, sh);
            sw += __shfl_xor(sw, sh);
        }
        if (m == 0) out[posg] = sw / se;
    }
}

// ---------------------------------------------------------------------------
// Recheck (R8 rework): ONE WAVE PER SUSPECT, grid-stride, uniform trip count.
// Old version batched 16 suspects per block with a serial per-suspect reduce
// containing 2 block barriers each (32 barriers/batch) and only nb<=~128
// active blocks. Now: grid 1024 x 4 waves = 4096 wave-slots; block iteration
// handles 4 suspects (one per wave); 1 barrier per iteration; lane l owns
// protos {l, l+64, l+128, l+192} (increasing-id scan -> first-occurrence
// tie-break preserved); fp64 math identical in kind (4-way split chains,
// ~1e-16 reassociation vs old order - far below any decision threshold).
// ---------------------------------------------------------------------------
__global__ __launch_bounds__(256)
void recheck_kernel(const float* __restrict__ qry, const double* __restrict__ pn64,
                    const int* __restrict__ valid, const int* __restrict__ counter,
                    const int* __restrict__ suspects, float* __restrict__ out)
{
    __shared__ float qsh[4][256];
    const int t = threadIdx.x;
    const int w = t >> 6, l = t & 63;
    int n = *counter; if (n > MAXSUS) n = MAXSUS;
    const int nb = (n + 3) >> 2;            // 4 suspects per block-iteration

    for (int batch = blockIdx.x; batch < nb; batch += gridDim.x) {
        const int si = batch * 4 + w;       // this wave's suspect
        const bool active = si < n;
        int pos = 0;
        if (active) {
            pos = suspects[si];
            // load q column: lane l loads c = l + 64*k into this wave's LDS row
#pragma unroll
            for (int k = 0; k < 4; ++k) {
                const int c = l + 64 * k;
                qsh[w][c] = qry[(size_t)(pos >> 12) * (C * HW) + (size_t)c * HW + (pos & (HW - 1))];
            }
        }
        __syncthreads();                    // qsh visible (uniform across block)
        if (active) {
            double best = -INFINITY; int bid = 0x7fffffff;
#pragma unroll
            for (int k = 0; k < 4; ++k) {
                const int p = l + 64 * k;   // increasing id order within lane
                if (valid[p]) {
                    const double* pr = pn64 + (size_t)p * C;
                    double a0 = 0.0, a1 = 0.0, a2 = 0.0, a3 = 0.0;
#pragma unroll 4
                    for (int c = 0; c < C; c += 4) {
                        a0 = fma((double)qsh[w][c + 0], pr[c + 0], a0);
                        a1 = fma((double)qsh[w][c + 1], pr[c + 1], a1);
                        a2 = fma((double)qsh[w][c + 2], pr[c + 2], a2);
                        a3 = fma((double)qsh[w][c + 3], pr[c + 3], a3);
                    }
                    const double d = (a0 + a1) + (a2 + a3);
                    if (d > best) { best = d; bid = p; }   // strict > keeps smallest id on ties
                }
            }
            // wave-wide reduce: max, smallest-id tie-break (first occurrence)
#pragma unroll
            for (int sh = 1; sh < 64; sh <<= 1) {
                const double od = __shfl_xor(best, sh);
                const int    oi = __shfl_xor(bid, sh);
                if (od > best || (od == best && oi < bid)) { best = od; bid = oi; }
            }
            if (l == 0) out[OUT_ASSIGN + pos] = (float)bid;
        }
        __syncthreads();                    // guard qsh overwrite next iteration
    }
}

// ---------------------------------------------------------------------------
extern "C" void kernel_launch(void* const* d_in, const int* in_sizes, int n_in,
                              void* d_out, int out_size, void* d_ws, size_t ws_size,
                              hipStream_t stream)
{
    const float* qry   = (const float*)d_in[0];
    const float* sup_x = (const float*)d_in[1];
    const float* sup_y = (const float*)d_in[2];
    float* out = (float*)d_out;
    char*  ws  = (char*)d_ws;

    // ws layout (~1.03 MiB total)
    unsigned short* pB       = (unsigned short*)(ws);            // 256 KiB frag-order split-bf16 protos
    double*         pn64     = (double*)(ws + 256 * 1024);       // 512 KiB
    int*            valid    = (int*)(ws + 768 * 1024);          // 1 KiB
    int*            counter  = (int*)(ws + 768 * 1024 + 1024);   // 4 B
    int*            suspects = (int*)(ws + 768 * 1024 + 2048);   // 256 KiB

    prep_kernel<<<dim3(P), dim3(256), 0, stream>>>(sup_x, sup_y, out, pB, pn64, valid, counter);
    dist_kernel<<<dim3(BQ * (HW / 64)), dim3(256), 0, stream>>>(qry, pB, valid, out, counter, suspects);
    recheck_kernel<<<dim3(1024), dim3(256), 0, stream>>>(qry, pn64, valid, counter, suspects, out);
}